// Round 2
// baseline (369.197 us; speedup 1.0000x reference)
//
#include <hip/hip_runtime.h>

// one_hot @ weight where one_hot rows are exact {0,1} one-hot rows.
// Dense GEMM == row gather, bit-exact in fp32.
//
// R1 lesson: per-block chunked early-exit (barrier + dependent reload) was
// latency-serialized -> 356 us. This version: barrier-free full streaming
// scan (pass 1) + row gather (pass 2). Fill kernels demonstrate 6.7 TB/s on
// this chip; pass 1 is the same regime.

constexpr int N_TOKENS = 8192;
constexpr int VOCAB    = 8192;   // = 2^13
constexpr int D        = 1024;
constexpr int BLOCK    = 256;

// Pass 1: find the hot column of each row. One float4 per thread, no loops,
// no barriers, pure stream. Only ~8192 of 16.7M threads take the store path.
__global__ __launch_bounds__(BLOCK) void scan_kernel(
    const float* __restrict__ one_hot,
    int* __restrict__ idx_buf) {
    const size_t e4 = (size_t)blockIdx.x * BLOCK + threadIdx.x; // float4 index
    const float4 v = ((const float4*)one_hot)[e4];
    if (v.x != 0.f || v.y != 0.f || v.z != 0.f || v.w != 0.f) {
        const int off = (v.x != 0.f) ? 0 : (v.y != 0.f) ? 1
                      : (v.z != 0.f) ? 2 : 3;
        const size_t flat = e4 * 4 + off;            // element index
        const int n = (int)(flat >> 13);             // / VOCAB
        const int c = (int)(flat & (VOCAB - 1));     // % VOCAB
        idx_buf[n] = c;                              // exactly one store per row
    }
}

// Pass 2: out[n] = weight[idx[n]]  (1024 floats = 256 lanes x float4)
__global__ __launch_bounds__(BLOCK) void gather_kernel(
    const int* __restrict__ idx_buf,
    const float* __restrict__ weight,
    float* __restrict__ out) {
    const int n = blockIdx.x;
    const int t = threadIdx.x;
    const int idx = idx_buf[n];
    float4* orow = (float4*)(out + (size_t)n * D);
    if ((unsigned)idx < (unsigned)VOCAB) {
        const float4* wrow = (const float4*)(weight + (size_t)idx * D);
        orow[t] = wrow[t];
    } else {
        // all-zero one_hot row (shouldn't happen) -> GEMM gives zeros;
        // also guards the 0xAA-poisoned workspace if a row never stored.
        orow[t] = make_float4(0.f, 0.f, 0.f, 0.f);
    }
}

extern "C" void kernel_launch(void* const* d_in, const int* in_sizes, int n_in,
                              void* d_out, int out_size, void* d_ws, size_t ws_size,
                              hipStream_t stream) {
    const float* one_hot = (const float*)d_in[0];   // [N_TOKENS, VOCAB] f32
    const float* weight  = (const float*)d_in[1];   // [VOCAB, D] f32
    float* out           = (float*)d_out;           // [N_TOKENS, D] f32
    int* idx_buf         = (int*)d_ws;              // 8192 ints (32 KB)

    const int total_f4 = N_TOKENS * VOCAB / 4;      // 16,777,216
    scan_kernel<<<dim3(total_f4 / BLOCK), dim3(BLOCK), 0, stream>>>(one_hot, idx_buf);
    gather_kernel<<<dim3(N_TOKENS), dim3(BLOCK), 0, stream>>>(idx_buf, weight, out);
}